// Round 11
// baseline (1636.933 us; speedup 1.0000x reference)
//
#include <hip/hip_runtime.h>
#include <stdint.h>
#include <math.h>

typedef unsigned short u16;
typedef unsigned int u32;

#define EPSF 1e-8f
#define SMOOTHF 9.0f
#define SLOPEF 0.1f

__device__ __forceinline__ u16 f2bf(float f) {
  union { float f; u32 u; } v; v.f = f;
  u32 u = v.u;
  u32 r = (u + 0x7FFFu + ((u >> 16) & 1u)) >> 16;   // RNE
  return (u16)r;
}
__device__ __forceinline__ float bf2f(u16 h) {
  union { u32 u; float f; } v; v.u = ((u32)h) << 16;
  return v.f;
}

__device__ __forceinline__ float wave_red_sum(float x) {
#pragma unroll
  for (int off = 32; off; off >>= 1) x += __shfl_xor(x, off, 64);
  return x;
}

__device__ __forceinline__ float block_red_sum(float x) {
  __shared__ float rs[4];
  x = wave_red_sum(x);
  const int lane = threadIdx.x & 63, wv = threadIdx.x >> 6;
  if (lane == 0) rs[wv] = x;
  __syncthreads();
  float r = rs[0] + rs[1] + rs[2] + rs[3];
  __syncthreads();
  return r;
}

// ---------------------------------------------------------------- small prep
__global__ __launch_bounds__(256) void rownorm_kernel(
    const float* __restrict__ cap, const float* __restrict__ img,
    float* __restrict__ capn, float* __restrict__ imgn) {
  const int row = blockIdx.x;  // 0..1279 cap rows, 1280..2431 img rows
  const float* p; float* o;
  if (row < 1280) { p = cap + (size_t)row * 1024; o = capn + row; }
  else            { p = img + (size_t)(row - 1280) * 1024; o = imgn + (row - 1280); }
  float ss = 0.f;
  for (int d = threadIdx.x; d < 1024; d += 256) { float v = p[d]; ss += v * v; }
  float t = block_red_sum(ss);
  if (threadIdx.x == 0) *o = sqrtf(t);
}

__global__ __launch_bounds__(256) void dup_kernel(
    const float* __restrict__ cap, int* __restrict__ dup) {
  const int b = blockIdx.x;
  const int c = b >> 5, i = b & 31;
  float ss = 0.f;
  if (c != i) {
    const float* A = cap + (size_t)c * 40960;
    const float* B = cap + (size_t)i * 40960;
    for (int e = threadIdx.x; e < 40960; e += 256) { float d = A[e] - B[e]; ss += d * d; }
  }
  float t = block_red_sum(ss);
  if (threadIdx.x == 0) dup[b] = (c != i && t <= 1e-6f) ? 1 : 0;
}

// Wcat row n: even n -> Wl[n/2], odd n -> Wg[n/2]
__global__ __launch_bounds__(256) void wconv_kernel(
    const float* __restrict__ Wl, const float* __restrict__ Wg, u16* __restrict__ out) {
  const size_t idx = ((size_t)blockIdx.x * 256 + threadIdx.x) * 4;
  const int n = (int)(idx >> 11);
  const int k = (int)(idx & 2047);
  const float* src = (n & 1) ? &Wg[(size_t)(n >> 1) * 2048 + k] : &Wl[(size_t)(n >> 1) * 2048 + k];
  float4 v = *(const float4*)src;
  ushort4 o;
  o.x = f2bf(v.x); o.y = f2bf(v.y); o.z = f2bf(v.z); o.w = f2bf(v.w);
  *(ushort4*)&out[idx] = o;
}

// fp32 rows -> bf16, grouped in 48-row padded blocks (pad rows zeroed).
__global__ __launch_bounds__(256) void bfpad_kernel(
    const float* __restrict__ src, u16* __restrict__ dst, int nrows) {
  const int b = blockIdx.x;
  const int blk = b / 48, r = b - blk * 48;
  u16* orow = dst + (size_t)b * 1024;
  const int tid = threadIdx.x;
  ushort4 o = {0, 0, 0, 0};
  if (r < nrows) {
    const float4 v = *(const float4*)&src[((size_t)blk * nrows + r) * 1024 + tid * 4];
    o.x = f2bf(v.x); o.y = f2bf(v.y); o.z = f2bf(v.z); o.w = f2bf(v.w);
  }
  *(ushort4*)&orow[tid * 4] = o;
}

// SS[b][s][s'] = src_b[s] . src_b[s'], fp32; zero outside nrows. grid (48, 32)
__global__ __launch_bounds__(256) void ss_kernel(
    const float* __restrict__ src, float* __restrict__ out, int nrows) {
  const int s = blockIdx.x, b = blockIdx.y;
  float* orow = out + ((size_t)b * 48 + s) * 64;
  __shared__ float Ls[1024];
  const int tid = threadIdx.x;
  if (s < nrows)
    *(float4*)&Ls[tid * 4] = *(const float4*)&src[((size_t)b * nrows + s) * 1024 + tid * 4];
  __syncthreads();
  const int s2 = tid >> 2, koff = (tid & 3) * 256;
  float acc = 0.f;
  if (s < nrows && s2 < nrows) {
    const float* r2 = src + ((size_t)b * nrows + s2) * 1024 + koff;
    for (int k = 0; k < 256; k += 4) {
      float4 a = *(const float4*)&Ls[koff + k];
      float4 bb = *(const float4*)&r2[k];
      acc += a.x * bb.x + a.y * bb.y + a.z * bb.z + a.w * bb.w;
    }
  }
  acc += __shfl_xor(acc, 1, 64);
  acc += __shfl_xor(acc, 2, 64);
  if ((tid & 3) == 0) orow[s2] = acc;
}

// ---------------------------------------------------------------- GEMMs
typedef short bf16x8 __attribute__((ext_vector_type(8)));
typedef float f32x4 __attribute__((ext_vector_type(4)));

#define GLDS(gp, lp)                                                                   \
  __builtin_amdgcn_global_load_lds((const __attribute__((address_space(1))) void*)(gp), \
                                   (__attribute__((address_space(3))) void*)(lp), 16, 0, 0)

// C[m][n] = sum_{k<1024} A[m*1024+k] * B[n*2048+koff+k], out bf16.
// trans=0: out[m*2048+n].  trans=1 (SWT): m=(blk*48+s) -> out[(blk*2048+n)*64+s].
__global__ __launch_bounds__(256) void gemm_flex_kernel(
    const u16* __restrict__ A, const u16* __restrict__ B, u16* __restrict__ Cout,
    int koff, int trans) {
  __shared__ u16 As[128 * 32];
  __shared__ u16 Bs[128 * 32];
  const int tid = threadIdx.x;
  const int lane = tid & 63;
  const int wave = tid >> 6;
  const int wm = (wave >> 1) * 64;
  const int wn = (wave & 1) * 64;
  const int bm = blockIdx.x * 128;
  const int bn = blockIdx.y * 128;
  const int lr = lane & 15;
  const int lq = lane >> 4;
  f32x4 acc[4][4] = {};
  const int e0 = tid * 8;
  const int r0 = e0 >> 5;
  const int c0 = e0 & 31;
  const u16* Ag0 = A + (size_t)(bm + r0) * 1024 + c0;
  const u16* Ag1 = A + (size_t)(bm + r0 + 64) * 1024 + c0;
  const u16* Bg0 = B + (size_t)(bn + r0) * 2048 + koff + c0;
  const u16* Bg1 = B + (size_t)(bn + r0 + 64) * 2048 + koff + c0;
  u16* As0 = As + e0; u16* As1 = As + e0 + 2048;
  u16* Bs0 = Bs + e0; u16* Bs1 = Bs + e0 + 2048;
  for (int k0 = 0; k0 < 1024; k0 += 32) {
    GLDS(Ag0 + k0, As0);
    GLDS(Ag1 + k0, As1);
    GLDS(Bg0 + k0, Bs0);
    GLDS(Bg1 + k0, Bs1);
    __syncthreads();
    bf16x8 af[4], bfr[4];
#pragma unroll
    for (int mi = 0; mi < 4; mi++)
      af[mi] = *(const bf16x8*)&As[(wm + mi * 16 + lr) * 32 + lq * 8];
#pragma unroll
    for (int ni = 0; ni < 4; ni++)
      bfr[ni] = *(const bf16x8*)&Bs[(wn + ni * 16 + lr) * 32 + lq * 8];
#pragma unroll
    for (int mi = 0; mi < 4; mi++)
#pragma unroll
      for (int ni = 0; ni < 4; ni++)
        acc[mi][ni] = __builtin_amdgcn_mfma_f32_16x16x32_bf16(af[mi], bfr[ni], acc[mi][ni], 0, 0, 0);
    __syncthreads();
  }
#pragma unroll
  for (int mi = 0; mi < 4; mi++) {
#pragma unroll
    for (int ni = 0; ni < 4; ni++) {
      const int col = bn + wn + ni * 16 + lr;
      const int rowb = bm + wm + mi * 16 + lq * 4;
      if (!trans) {
#pragma unroll
        for (int r = 0; r < 4; r++)
          Cout[(size_t)(rowb + r) * 2048 + col] = f2bf(acc[mi][ni][r]);
      } else {
#pragma unroll
        for (int r = 0; r < 4; r++) {
          const int m = rowb + r;
          const int blk = m / 48, s = m - blk * 48;
          Cout[((size_t)blk * 2048 + col) * 64 + s] = f2bf(acc[mi][ni][r]);
        }
      }
    }
  }
}

// E[m][n] = sum_k imgbf[m][k]*capbf[n][k], fp32 out, M=N=1536, K=1024. grid (12,12)
__global__ __launch_bounds__(256) void gemm_e_kernel(
    const u16* __restrict__ A, const u16* __restrict__ B, float* __restrict__ C) {
  __shared__ u16 As[128 * 32];
  __shared__ u16 Bs[128 * 32];
  const int tid = threadIdx.x;
  const int lane = tid & 63;
  const int wave = tid >> 6;
  const int wm = (wave >> 1) * 64;
  const int wn = (wave & 1) * 64;
  const int bm = blockIdx.x * 128;
  const int bn = blockIdx.y * 128;
  const int lr = lane & 15;
  const int lq = lane >> 4;
  f32x4 acc[4][4] = {};
  const int e0 = tid * 8;
  const int r0 = e0 >> 5;
  const int c0 = e0 & 31;
  const u16* Ag0 = A + (size_t)(bm + r0) * 1024 + c0;
  const u16* Ag1 = A + (size_t)(bm + r0 + 64) * 1024 + c0;
  const u16* Bg0 = B + (size_t)(bn + r0) * 1024 + c0;
  const u16* Bg1 = B + (size_t)(bn + r0 + 64) * 1024 + c0;
  u16* As0 = As + e0; u16* As1 = As + e0 + 2048;
  u16* Bs0 = Bs + e0; u16* Bs1 = Bs + e0 + 2048;
  for (int k0 = 0; k0 < 1024; k0 += 32) {
    GLDS(Ag0 + k0, As0);
    GLDS(Ag1 + k0, As1);
    GLDS(Bg0 + k0, Bs0);
    GLDS(Bg1 + k0, Bs1);
    __syncthreads();
    bf16x8 af[4], bfr[4];
#pragma unroll
    for (int mi = 0; mi < 4; mi++)
      af[mi] = *(const bf16x8*)&As[(wm + mi * 16 + lr) * 32 + lq * 8];
#pragma unroll
    for (int ni = 0; ni < 4; ni++)
      bfr[ni] = *(const bf16x8*)&Bs[(wn + ni * 16 + lr) * 32 + lq * 8];
#pragma unroll
    for (int mi = 0; mi < 4; mi++)
#pragma unroll
      for (int ni = 0; ni < 4; ni++)
        acc[mi][ni] = __builtin_amdgcn_mfma_f32_16x16x32_bf16(af[mi], bfr[ni], acc[mi][ni], 0, 0, 0);
    __syncthreads();
  }
#pragma unroll
  for (int mi = 0; mi < 4; mi++)
#pragma unroll
    for (int ni = 0; ni < 4; ni++) {
      const int col = bn + wn + ni * 16 + lr;
      const int rowb = bm + wm + mi * 16 + lq * 4;
#pragma unroll
      for (int r = 0; r < 4; r++)
        C[(size_t)(rowb + r) * 1536 + col] = acc[mi][ni][r];
    }
}

// ---------------------------------------------------------------- wcgate GEMM
// u-rows: M = P*NQ, m = pl*NQ+q, pairs sIdx-grouped (sIdx = (p0+pl)>>5).
// acc[m][n] = attnTg[m][0:64].SWT[sIdx][n][0:64]  (+ STEP==1: q1[m][0:1024].Wcat[n][0:1024])
// Tile BM x 256, BK=64, 8 waves (2Mx4N, per-wave BM/2 x 64), 2-phase dbuf;
// XOR-swizzled LDS (linear dest + pre-swizzled global col + same XOR on ds_read).
// R11: XCD raster ALWAYS on via padded grid — gridDim.y = ceil(Mt/8)*8; ghost
// blocks (bmi >= mt) return immediately. bmi=(b&7)+(b>>6)*8, bni=(b>>3)&7 keeps
// all 8 blocks sharing an A-panel on XCD bmi%8 (A + qv: HBM once, then local L2).
// STEP==0: BM=128, qv+QW0 staged in the single-tile latency window (R6-verified).
// STEP==1: BM=256 (t2i) / 192 (i2t); qvS/stash overlay the dead dbuf halves.
template <int STEP, int NQ, int BM>
__global__ __launch_bounds__(512) void wcgate_kernel(
    const u16* __restrict__ attnTg, const u16* __restrict__ q2nd,
    const u16* __restrict__ qref, const u16* __restrict__ SWT,
    const u16* __restrict__ Wcat, const u16* __restrict__ qw0,
    const float* __restrict__ bl, const float* __restrict__ bg,
    u16* __restrict__ Uout, int p0, int mt) {
  constexpr int NT = (STEP == 1) ? 17 : 1;     // K tiles of 64
  constexpr int BUF = (BM + 256) * 64;         // u16 per buffer (A tile + B tile)
  constexpr int WMR = BM / 32;                 // per-wave M fragments
  constexpr int APASS = BM / 64;               // A staging passes of 512 chunks
  constexpr int QPASS = BM / 32;               // qv staging / stash-store passes
  __shared__ u16 sh[(STEP == 0) ? 73728 : 2 * BUF];
  const int tid = threadIdx.x;
  const int lane = tid & 63;
  const int wave = tid >> 6;
  const int wr = wave >> 2, wc = wave & 3;
  const int wm = wr * (BM / 2), wn = wc * 64;
  const int lr = lane & 15, lq = lane >> 4;
  const int b = blockIdx.y * 8 + blockIdx.x;
  const int bmi = (b & 7) + (b >> 6) * 8;
  const int bni = (b >> 3) & 7;
  if (bmi >= mt) return;                       // ghost block (padded grid)
  const int bm = bmi * BM;
  const int bn = bni * 256;
  const int sIdx = (p0 + bm / NQ) >> 5;
  f32x4 acc[WMR][4] = {};

  // per-thread staging descriptors, swizzled source col
  int aoff[APASS]; const u16* asrc0[APASS]; const u16* asrcW[APASS];
  int boff[4]; const u16* bsrc0[4]; const u16* bsrcW[4];
#pragma unroll
  for (int p = 0; p < APASS; p++) {
    const int c = p * 512 + tid;
    const int row = c >> 3, sub = c & 7;
    const int sw = (sub ^ (row & 7)) << 3;
    aoff[p] = c * 8;
    asrc0[p] = attnTg + (size_t)(bm + row) * 64 + sw;
    asrcW[p] = q2nd + (size_t)(bm + row) * 1024 + sw;
  }
#pragma unroll
  for (int p = 0; p < 4; p++) {
    const int c = p * 512 + tid;
    const int row = c >> 3, sub = c & 7;
    const int sw = (sub ^ (row & 7)) << 3;
    boff[p] = c * 8;
    bsrc0[p] = SWT + ((size_t)sIdx * 2048 + bn + row) * 64 + sw;
    bsrcW[p] = Wcat + (size_t)(bn + row) * 2048 + sw;
  }

  u16* const qvS = (STEP == 0) ? sh + 24576 : sh + BUF;    // [BM][128] u16
  u16* const qw0S = sh + 40960;                            // [128][256] u16 (step0)
  u16* const stash = sh;                                   // [BM][128] u16 overlay

  auto epi_stage = [&]() {
#pragma unroll
    for (int p = 0; p < QPASS; p++) {          // qv: BM x 128 u16
      const int c = p * 512 + tid;
      const int row = c >> 4, j = c & 15;
      const u16* src;
      if (STEP == 1) {
        src = qref + (size_t)(bm + row) * 1024 + (bn >> 1) + j * 8;
      } else {
        const int m = bm + row;
        const int pl = m / NQ;                 // compile-time NQ -> magic mul
        const int q = m - pl * NQ;
        const int gs = ((p0 + pl) & 31) * 48 + q;
        src = qref + (size_t)gs * 1024 + (bn >> 1) + j * 8;
      }
      GLDS(src, qvS + c * 8);
    }
    if (STEP == 0) {
#pragma unroll
      for (int p = 0; p < 8; p++) {            // qw0 pairs: 128 x 256 u16 (512B rows)
        const int c = p * 512 + tid;
        const int row = c >> 5, j = c & 31;
        const int m = bm + row;
        const int pl = m / NQ;
        const int q = m - pl * NQ;
        const int gs = ((p0 + pl) & 31) * 48 + q;
        GLDS(qw0 + (size_t)gs * 2048 + bn + j * 8, qw0S + c * 8);
      }
    }
  };

  auto compute = [&](const u16* A, const u16* B) {
#pragma unroll
    for (int kk = 0; kk < 2; kk++) {
      bf16x8 bfv[4];
#pragma unroll
      for (int ni = 0; ni < 4; ni++) {
        const int rb = wn + ni * 16 + lr;
        bfv[ni] = *(const bf16x8*)&B[rb * 64 + ((kk * 32 + lq * 8) ^ ((rb & 7) << 3))];
      }
#pragma unroll
      for (int mi = 0; mi < WMR; mi++) {
        const int ra = wm + mi * 16 + lr;
        const bf16x8 af = *(const bf16x8*)&A[ra * 64 + ((kk * 32 + lq * 8) ^ ((ra & 7) << 3))];
#pragma unroll
        for (int ni = 0; ni < 4; ni++)
          acc[mi][ni] = __builtin_amdgcn_mfma_f32_16x16x32_bf16(af, bfv[ni], acc[mi][ni], 0, 0, 0);
      }
    }
  };

  if constexpr (STEP == 0) {
    // single SWT K-tile; epilogue operands staged in the same latency window
#pragma unroll
    for (int p = 0; p < APASS; p++) GLDS(asrc0[p], sh + aoff[p]);
#pragma unroll
    for (int p = 0; p < 4; p++) GLDS(bsrc0[p], sh + BM * 64 + boff[p]);
    epi_stage();                               // 12 more GLDS per thread in flight
    asm volatile("s_waitcnt vmcnt(12)" ::: "memory");  // first 6 (tile 0) landed
    __builtin_amdgcn_sched_barrier(0);
    __builtin_amdgcn_s_barrier();
    compute(sh, sh + BM * 64);
    __syncthreads();                           // drains epi GLDS + LDS reads
  } else {
    // tile 0 = attnTg/SWT; tiles 1..16 = q2nd/Wcat with kt = tt
#pragma unroll
    for (int p = 0; p < APASS; p++) GLDS(asrc0[p], sh + aoff[p]);
#pragma unroll
    for (int p = 0; p < 4; p++) GLDS(bsrc0[p], sh + BM * 64 + boff[p]);
    __syncthreads();
#pragma unroll
    for (int tt = 0; tt < NT; ++tt) {
      u16* cur = sh + (tt & 1) * BUF;
      u16* nxt = sh + ((tt & 1) ^ 1) * BUF;
      if (tt < NT - 1) {                       // stage Wcat tile kt=tt into nxt
#pragma unroll
        for (int p = 0; p < APASS; p++) GLDS(asrcW[p] + tt * 64, nxt + aoff[p]);
#pragma unroll
        for (int p = 0; p < 4; p++) GLDS(bsrcW[p] + tt * 64, nxt + BM * 64 + boff[p]);
      } else {
        epi_stage();                           // qv loads fly under last compute
      }
      compute(cur, cur + BM * 64);
      __syncthreads();                         // drains vmcnt + lgkm
    }
  }

  // pairwise epilogue: even lane owns row base+rr, odd lane row base+rr+1
  const bool evn = (lane & 1) == 0;
#pragma unroll
  for (int ni = 0; ni < 4; ni++) {
    const int ncol = wn + ni * 16 + lr;        // local n in [0,256)
    const int dloc = ncol >> 1;                // local d in [0,128), same for pair
    const float blv = bl[(bn >> 1) + dloc];
    const float bgv = bg[(bn >> 1) + dloc];
#pragma unroll
    for (int mi = 0; mi < WMR; mi++) {
      const int base = wm + mi * 16 + lq * 4;
#pragma unroll
      for (int rr = 0; rr < 4; rr += 2) {
        const float a0 = acc[mi][ni][rr];
        const float a1 = acc[mi][ni][rr + 1];
        const float o0 = __shfl_xor(a0, 1, 64);
        const float o1 = __shfl_xor(a1, 1, 64);
        float lin2 = (evn ? a0 : o1) + blv;
        float gt = (evn ? o0 : a1) + bgv;
        const int rl = base + rr + (evn ? 0 : 1);
        if constexpr (STEP == 0) {
          const u32 pair = *(const u32*)&qw0S[rl * 256 + dloc * 2];
          lin2 += bf2f((u16)(pair & 0xffffu));
          gt += bf2f((u16)(pair >> 16));
        }
        const float qv = bf2f(qvS[rl * 128 + dloc]);
        lin2 = fminf(fmaxf(lin2, -30.f), 30.f);
        gt = fminf(fmaxf(gt, -30.f), 30.f);
        const float gg = 1.f / (1.f + __expf(-gt));
        const float e2 = __expf(-2.f * lin2);
        const float th = (1.f - e2) / (1.f + e2);
        const float u = qv * gg + th * (1.f - gg);
        stash[rl * 128 + dloc] = f2bf(u);
      }
    }
  }
  __syncthreads();
  // coalesced store of BM x 128 u16 tile
#pragma unroll
  for (int p = 0; p < QPASS; p++) {
    const int c = p * 512 + tid;
    const int row = c >> 4, j = c & 15;
    *(bf16x8*)(Uout + (size_t)(bm + row) * 1024 + (bn >> 1) + j * 8) =
        *(const bf16x8*)&stash[row * 128 + j * 8];
  }
}

// q_new = u / (||u|| + eps), in-place (M x 1024 bf16). One wave per row.
__global__ __launch_bounds__(256) void qnorm_kernel(u16* __restrict__ Q) {
  const int m = blockIdx.x * 4 + (threadIdx.x >> 6);
  const int lane = threadIdx.x & 63;
  u16* p = Q + (size_t)m * 1024;
  float v[16];
  float ss = 0.f;
#pragma unroll
  for (int t = 0; t < 4; t++) {
    ushort4 uv = *(const ushort4*)&p[t * 256 + lane * 4];
    float a = bf2f(uv.x), b = bf2f(uv.y), c = bf2f(uv.z), dd = bf2f(uv.w);
    v[t * 4 + 0] = a; v[t * 4 + 1] = b; v[t * 4 + 2] = c; v[t * 4 + 3] = dd;
    ss += a * a + b * b + c * c + dd * dd;
  }
  ss = wave_red_sum(ss);
  const float inv = 1.f / (sqrtf(ss) + EPSF);
#pragma unroll
  for (int t = 0; t < 4; t++) {
    ushort4 ov;
    ov.x = f2bf(v[t * 4 + 0] * inv); ov.y = f2bf(v[t * 4 + 1] * inv);
    ov.z = f2bf(v[t * 4 + 2] * inv); ov.w = f2bf(v[t * 4 + 3] * inv);
    *(ushort4*)&p[t * 256 + lane * 4] = ov;
  }
}

// ---------------------------------------------------------------- fused attention step
// A (steps 1,2): QK^T MFMA; step0: logits = E block. B: leaky/l2norm/softmax (fp32).
// C': num = a.E-col, pss = a^T SS a (LDS algebra). Writes attnT (steps 0,1).
template <int NS, int NQ>
__global__ __launch_bounds__(256) void attn_step_kernel(
    const u16* __restrict__ Sbf, const float* __restrict__ E,
    const float* __restrict__ SS, const float* __restrict__ refn,
    const u16* __restrict__ qsrc, u16* __restrict__ attnTg,
    const int* __restrict__ dup, float* __restrict__ total,
    int p0, int t2i, int step) {
  constexpr int NQW = NQ / 4;
  const int pl = blockIdx.x;
  const int plg = p0 + pl;                 // pairs sIdx-grouped
  const int sIdx = plg >> 5, rIdx = plg & 31;
  const int c = t2i ? rIdx : sIdx;
  const int i = t2i ? sIdx : rIdx;
  const int gp = c * 32 + i;
  const u16* Sb = Sbf + (size_t)sIdx * 48 * 1024;
  const float* rn = refn + (size_t)rIdx * NQ;
  const u16* Qb = qsrc + (size_t)pl * NQ * 1024;

  __shared__ float redbuf[9600];   // phase A red[4][2400]; later Elw[48*65] + SSl[48*65]
  __shared__ float attnS[2304];
  __shared__ float redcos[48];
  float* Elw = redbuf;
  float* SSl = redbuf + 3120;

  const int tid = threadIdx.x;
  const int lane = tid & 63, wave = tid >> 6;
  const int lr = lane & 15, quad = lane >> 4;

  if (step == 0) {
    for (int e = tid; e < 2304; e += 256) {
      int s, q; float v;
      if (t2i) { s = e / 48; q = e - s * 48; v = E[(size_t)(i * 48 + s) * 1536 + c * 48 + q]; }
      else     { q = e / 48; s = e - q * 48; v = E[(size_t)(i * 48 + q) * 1536 + c * 48 + s]; }
      attnS[s * 48 + q] = v;
    }
  } else {
    // phase A: wave w covers k in [w*256, w*256+256); 8 slabs x 3x3 MFMA frags
    f32x4 acc[3][3] = {};
    const int kw = wave * 256;
    const u16* Arow[3]; const u16* Brow[3];
#pragma unroll
    for (int a = 0; a < 3; a++) {
      Arow[a] = Sb + (size_t)(a * 16 + lr) * 1024 + quad * 8;
      Brow[a] = Qb + (size_t)(a * 16 + lr) * 1024 + quad * 8;
    }
    bf16x8 A0[3], B0[3], A1[3], B1[3];
#pragma unroll
    for (int a = 0; a < 3; a++) {
      A0[a] = *(const bf16x8*)(Arow[a] + kw);
      B0[a] = *(const bf16x8*)(Brow[a] + kw);
    }
#pragma unroll
    for (int j = 0; j < 8; j++) {
      if (j < 7) {
        const int kn = kw + (j + 1) * 32;
#pragma unroll
        for (int a = 0; a < 3; a++) {
          A1[a] = *(const bf16x8*)(Arow[a] + kn);
          B1[a] = *(const bf16x8*)(Brow[a] + kn);
        }
      }
#pragma unroll
      for (int a = 0; a < 3; a++)
#pragma unroll
        for (int b = 0; b < 3; b++)
          acc[a][b] = __builtin_amdgcn_mfma_f32_16x16x32_bf16(A0[a], B0[b], acc[a][b], 0, 0, 0);
#pragma unroll
      for (int a = 0; a < 3; a++) { A0[a] = A1[a]; B0[a] = B1[a]; }
    }
    float* myred = redbuf + wave * 2400;
#pragma unroll
    for (int a = 0; a < 3; a++)
#pragma unroll
      for (int b = 0; b < 3; b++) {
        const int col = b * 16 + lr;
        const int row0 = a * 16 + quad * 4;
#pragma unroll
        for (int r = 0; r < 4; r++)
          myred[(row0 + r) * 50 + col] = acc[a][b][r];
      }
    __syncthreads();
#pragma unroll
    for (int t = 0; t < 9; t++) {
      const int e = tid + t * 256;
      const int s = e / 48, q = e - s * 48;
      const int o = s * 50 + q;
      attnS[e] = redbuf[o] + redbuf[2400 + o] + redbuf[4800 + o] + redbuf[7200 + o];
    }
  }
  __syncthreads();
  // load Elw / SSl (into dead red space) + leaky/l2norm in one interval
  for (int e = tid; e < 2304; e += 256) {
    int s, q; float v;
    if (t2i) { s = e / 48; q = e - s * 48; v = E[(size_t)(i * 48 + s) * 1536 + c * 48 + q]; }
    else     { q = e / 48; s = e - q * 48; v = E[(size_t)(i * 48 + q) * 1536 + c * 48 + s]; }
    Elw[s * 65 + q] = v;
  }
  for (int e = tid; e < 48 * 64; e += 256) {
    const int s = e >> 6, s2 = e & 63;
    SSl[s * 65 + s2] = SS[((size_t)sIdx * 48 + s) * 64 + s2];
  }
  if (tid < NS) {
    float row[NQ];
    float ss = 0.f;
#pragma unroll
    for (int q = 0; q < NQ; q++) {
      float v = attnS[tid * 48 + q];
      v = (v > 0.f) ? v : SLOPEF * v;
      row[q] = v; ss += v * v;
    }
    const float inv = 1.f / (sqrtf(ss) + EPSF);
#pragma unroll
    for (int q = 0; q < NQ; q++) attnS[tid * 48 + q] = row[q] * inv;
  }
  __syncthreads();
  if (tid < NQ) {
    float mx = -1e30f;
#pragma unroll
    for (int s = 0; s < NS; s++) mx = fmaxf(mx, attnS[s * 48 + tid]);
    float ex[NS]; float sum = 0.f;
#pragma unroll
    for (int s = 0; s < NS; s++) {
      float t = __expf(SMOOTHF * (attnS[s * 48 + tid] - mx));
      ex[s] = t; sum += t;
    }
    const float inv = 1.f / sum;
#pragma unroll
    for (int s = 0; s < NS; s++) attnS[s * 48 + tid] = ex[s] * inv;
  }
  __syncthreads();
  // write attnT rows (steps 0,1): [m = pl*NQ+q][64 s]
  if (step < 2) {
    for (int e = tid; e < NQ * 64; e += 256) {
      const int q = e >> 6, s = e & 63;
      attnTg[((size_t)(pl * NQ + q)) * 64 + s] = (s < 48) ? f2bf(attnS[s * 48 + q]) : (u16)0;
    }
  }
  // phase C': per-q num & pss via E/SS algebra
  {
    const int qbase = wave * NQW;
#pragma unroll
    for (int qq = 0; qq < NQW; qq++) {
      const int q = qbase + qq;
      const float a_l = (lane < 48) ? attnS[lane * 48 + q] : 0.f;
      float t = 0.f;
#pragma unroll
      for (int s = 0; s < NS; s++)
        t += attnS[s * 48 + q] * SSl[s * 65 + lane];
      float pssv = wave_red_sum(a_l * t);
      float numv = wave_red_sum(a_l * Elw[lane * 65 + q]);
      if (lane == 0) redcos[q] = numv / fmaxf(rn[q] * sqrtf(pssv), EPSF);
    }
  }
  __syncthreads();
  if (tid == 0) {
    float sim = 0.f;
#pragma unroll
    for (int q = 0; q < NQ; q++) sim += redcos[q];
    sim *= (1.0f / NQ);
    atomicAdd(&total[gp], dup[gp] ? -1.0f : sim);
  }
}

// ---------------------------------------------------------------- launcher
extern "C" void kernel_launch(void* const* d_in, const int* in_sizes, int n_in,
                              void* d_out, int out_size, void* d_ws, size_t ws_size,
                              hipStream_t stream) {
  (void)in_sizes; (void)n_in;
  const float* img = (const float*)d_in[0];
  const float* cap = (const float*)d_in[1];
  const float* W_lt2i = (const float*)d_in[2];
  const float* b_lt2i = (const float*)d_in[3];
  const float* W_gt2i = (const float*)d_in[4];
  const float* b_gt2i = (const float*)d_in[5];
  const float* W_li2t = (const float*)d_in[6];
  const float* b_li2t = (const float*)d_in[7];
  const float* W_gi2t = (const float*)d_in[8];
  const float* b_gi2t = (const float*)d_in[9];
  float* total = (float*)d_out;

  char* ws = (char*)d_ws;
  size_t off = 0;
  auto alloc = [&](size_t b) { void* p = ws + off; off += (b + 255) & ~(size_t)255; return p; };
  u16* Wcat = (u16*)alloc((size_t)2048 * 2048 * 2);
  u16* imgbf = (u16*)alloc((size_t)32 * 48 * 1024 * 2);
  u16* capbf = (u16*)alloc((size_t)32 * 48 * 1024 * 2);
  float* capn = (float*)alloc(1280 * 4);
  float* imgn = (float*)alloc(1152 * 4);
  int* dupb = (int*)alloc(1024 * 4);
  u16* SWT = (u16*)alloc((size_t)32 * 2048 * 64 * 2);
  float* E = (float*)alloc((size_t)1536 * 1536 * 4);
  float* SSi = (float*)alloc((size_t)32 * 48 * 64 * 4);
  float* SSc = (float*)alloc((size_t)32 * 48 * 64 * 4);
  u16* QW0 = (u16*)alloc((size_t)1536 * 2048 * 2);
  const size_t fixed = off;

  static const int cands[6] = {1024, 512, 256, 128, 64, 32};
  int P = 32;
  for (int ci = 0; ci < 6; ci++) {
    const int cand = cands[ci];
    const size_t cA = (((size_t)cand * 40 * 1024 * 2) + 255) & ~(size_t)255;
    const size_t aT = (((size_t)cand * 40 * 64 * 2) + 255) & ~(size_t)255;
    if (fixed + 2 * cA + aT <= ws_size) { P = cand; break; }
  }
  u16* catA = (u16*)alloc((size_t)P * 40 * 1024 * 2);
  u16* catB = (u16*)alloc((size_t)P * 40 * 1024 * 2);
  u16* attnTg = (u16*)alloc((size_t)P * 40 * 64 * 2);

  hipMemsetAsync(d_out, 0, (size_t)out_size * sizeof(float), stream);
  hipMemsetAsync(SWT, 0, (size_t)32 * 2048 * 64 * 2, stream);
  rownorm_kernel<<<dim3(2432), dim3(256), 0, stream>>>(cap, img, capn, imgn);
  dup_kernel<<<dim3(1024), dim3(256), 0, stream>>>(cap, dupb);
  bfpad_kernel<<<dim3(1536), dim3(256), 0, stream>>>(cap, capbf, 40);
  bfpad_kernel<<<dim3(1536), dim3(256), 0, stream>>>(img, imgbf, 36);
  gemm_e_kernel<<<dim3(12, 12), dim3(256), 0, stream>>>(imgbf, capbf, E);
  ss_kernel<<<dim3(48, 32), dim3(256), 0, stream>>>(img, SSi, 36);
  ss_kernel<<<dim3(48, 32), dim3(256), 0, stream>>>(cap, SSc, 40);

  const int nch = 1024 / P;
  for (int dir = 0; dir < 2; dir++) {
    const int t2i = (dir == 0) ? 1 : 0;
    const float* Wl = t2i ? W_lt2i : W_li2t;
    const float* Wg = t2i ? W_gt2i : W_gi2t;
    const float* bl = t2i ? b_lt2i : b_li2t;
    const float* bg = t2i ? b_gt2i : b_gi2t;
    const u16* Sbf = t2i ? imgbf : capbf;
    const u16* Refbf = t2i ? capbf : imgbf;
    const float* SSd = t2i ? SSi : SSc;
    const float* refn = t2i ? capn : imgn;
    const int NQ = t2i ? 40 : 36;
    const int BM1 = t2i ? 256 : 192;           // step-1 tile (sIdx-group aligned)
    const int Mrows = P * NQ;
    const int Mt0 = Mrows / 128;
    const int Mt1 = Mrows / BM1;
    const int Mt0p = (Mt0 + 7) & ~7;           // padded grids: swizzle always on,
    const int Mt1p = (Mt1 + 7) & ~7;           // ghost blocks early-exit
    wconv_kernel<<<dim3(4096), dim3(256), 0, stream>>>(Wl, Wg, Wcat);
    gemm_flex_kernel<<<dim3(12, 16), dim3(256), 0, stream>>>(Sbf, Wcat, SWT, 1024, 1);
    gemm_flex_kernel<<<dim3(12, 16), dim3(256), 0, stream>>>(Refbf, Wcat, QW0, 0, 0);
    for (int ch = 0; ch < nch; ch++) {
      const int p0 = ch * P;
      for (int step = 0; step < 3; step++) {
        const u16* qsrc = (step == 1) ? catB : catA;
        if (t2i)
          attn_step_kernel<36, 40><<<dim3(P), dim3(256), 0, stream>>>(
              Sbf, E, SSd, refn, qsrc, attnTg, dupb, total, p0, 1, step);
        else
          attn_step_kernel<40, 36><<<dim3(P), dim3(256), 0, stream>>>(
              Sbf, E, SSd, refn, qsrc, attnTg, dupb, total, p0, 0, step);
        if (step == 0) {
          if (t2i)
            wcgate_kernel<0, 40, 128><<<dim3(8, Mt0p), dim3(512), 0, stream>>>(
                attnTg, catA, Refbf, SWT, Wcat, QW0, bl, bg, catB, p0, Mt0);
          else
            wcgate_kernel<0, 36, 128><<<dim3(8, Mt0p), dim3(512), 0, stream>>>(
                attnTg, catA, Refbf, SWT, Wcat, QW0, bl, bg, catB, p0, Mt0);
          qnorm_kernel<<<dim3(Mrows / 4), dim3(256), 0, stream>>>(catB);
        } else if (step == 1) {
          if (t2i)
            wcgate_kernel<1, 40, 256><<<dim3(8, Mt1p), dim3(512), 0, stream>>>(
                attnTg, catB, catB, SWT, Wcat, QW0, bl, bg, catA, p0, Mt1);
          else
            wcgate_kernel<1, 36, 192><<<dim3(8, Mt1p), dim3(512), 0, stream>>>(
                attnTg, catB, catB, SWT, Wcat, QW0, bl, bg, catA, p0, Mt1);
          qnorm_kernel<<<dim3(Mrows / 4), dim3(256), 0, stream>>>(catA);
        }
      }
    }
  }
}

// Round 12
// 1406.658 us; speedup vs baseline: 1.1637x; 1.1637x over previous
//
#include <hip/hip_runtime.h>
#include <stdint.h>
#include <math.h>

typedef unsigned short u16;
typedef unsigned int u32;

#define EPSF 1e-8f
#define SMOOTHF 9.0f
#define SLOPEF 0.1f

__device__ __forceinline__ u16 f2bf(float f) {
  union { float f; u32 u; } v; v.f = f;
  u32 u = v.u;
  u32 r = (u + 0x7FFFu + ((u >> 16) & 1u)) >> 16;   // RNE
  return (u16)r;
}
__device__ __forceinline__ float bf2f(u16 h) {
  union { u32 u; float f; } v; v.u = ((u32)h) << 16;
  return v.f;
}

__device__ __forceinline__ float wave_red_sum(float x) {
#pragma unroll
  for (int off = 32; off; off >>= 1) x += __shfl_xor(x, off, 64);
  return x;
}

__device__ __forceinline__ float block_red_sum(float x) {
  __shared__ float rs[4];
  x = wave_red_sum(x);
  const int lane = threadIdx.x & 63, wv = threadIdx.x >> 6;
  if (lane == 0) rs[wv] = x;
  __syncthreads();
  float r = rs[0] + rs[1] + rs[2] + rs[3];
  __syncthreads();
  return r;
}

// ---------------------------------------------------------------- small prep
__global__ __launch_bounds__(256) void rownorm_kernel(
    const float* __restrict__ cap, const float* __restrict__ img,
    float* __restrict__ capn, float* __restrict__ imgn) {
  const int row = blockIdx.x;  // 0..1279 cap rows, 1280..2431 img rows
  const float* p; float* o;
  if (row < 1280) { p = cap + (size_t)row * 1024; o = capn + row; }
  else            { p = img + (size_t)(row - 1280) * 1024; o = imgn + (row - 1280); }
  float ss = 0.f;
  for (int d = threadIdx.x; d < 1024; d += 256) { float v = p[d]; ss += v * v; }
  float t = block_red_sum(ss);
  if (threadIdx.x == 0) *o = sqrtf(t);
}

__global__ __launch_bounds__(256) void dup_kernel(
    const float* __restrict__ cap, int* __restrict__ dup) {
  const int b = blockIdx.x;
  const int c = b >> 5, i = b & 31;
  float ss = 0.f;
  if (c != i) {
    const float* A = cap + (size_t)c * 40960;
    const float* B = cap + (size_t)i * 40960;
    for (int e = threadIdx.x; e < 40960; e += 256) { float d = A[e] - B[e]; ss += d * d; }
  }
  float t = block_red_sum(ss);
  if (threadIdx.x == 0) dup[b] = (c != i && t <= 1e-6f) ? 1 : 0;
}

// Wcat row n: even n -> Wl[n/2], odd n -> Wg[n/2]
__global__ __launch_bounds__(256) void wconv_kernel(
    const float* __restrict__ Wl, const float* __restrict__ Wg, u16* __restrict__ out) {
  const size_t idx = ((size_t)blockIdx.x * 256 + threadIdx.x) * 4;
  const int n = (int)(idx >> 11);
  const int k = (int)(idx & 2047);
  const float* src = (n & 1) ? &Wg[(size_t)(n >> 1) * 2048 + k] : &Wl[(size_t)(n >> 1) * 2048 + k];
  float4 v = *(const float4*)src;
  ushort4 o;
  o.x = f2bf(v.x); o.y = f2bf(v.y); o.z = f2bf(v.z); o.w = f2bf(v.w);
  *(ushort4*)&out[idx] = o;
}

// fp32 rows -> bf16, grouped in 48-row padded blocks (pad rows zeroed).
__global__ __launch_bounds__(256) void bfpad_kernel(
    const float* __restrict__ src, u16* __restrict__ dst, int nrows) {
  const int b = blockIdx.x;
  const int blk = b / 48, r = b - blk * 48;
  u16* orow = dst + (size_t)b * 1024;
  const int tid = threadIdx.x;
  ushort4 o = {0, 0, 0, 0};
  if (r < nrows) {
    const float4 v = *(const float4*)&src[((size_t)blk * nrows + r) * 1024 + tid * 4];
    o.x = f2bf(v.x); o.y = f2bf(v.y); o.z = f2bf(v.z); o.w = f2bf(v.w);
  }
  *(ushort4*)&orow[tid * 4] = o;
}

// SS[b][s][s'] = src_b[s] . src_b[s'], fp32; zero outside nrows. grid (48, 32)
__global__ __launch_bounds__(256) void ss_kernel(
    const float* __restrict__ src, float* __restrict__ out, int nrows) {
  const int s = blockIdx.x, b = blockIdx.y;
  float* orow = out + ((size_t)b * 48 + s) * 64;
  __shared__ float Ls[1024];
  const int tid = threadIdx.x;
  if (s < nrows)
    *(float4*)&Ls[tid * 4] = *(const float4*)&src[((size_t)b * nrows + s) * 1024 + tid * 4];
  __syncthreads();
  const int s2 = tid >> 2, koff = (tid & 3) * 256;
  float acc = 0.f;
  if (s < nrows && s2 < nrows) {
    const float* r2 = src + ((size_t)b * nrows + s2) * 1024 + koff;
    for (int k = 0; k < 256; k += 4) {
      float4 a = *(const float4*)&Ls[koff + k];
      float4 bb = *(const float4*)&r2[k];
      acc += a.x * bb.x + a.y * bb.y + a.z * bb.z + a.w * bb.w;
    }
  }
  acc += __shfl_xor(acc, 1, 64);
  acc += __shfl_xor(acc, 2, 64);
  if ((tid & 3) == 0) orow[s2] = acc;
}

// ---------------------------------------------------------------- GEMMs
typedef short bf16x8 __attribute__((ext_vector_type(8)));
typedef float f32x4 __attribute__((ext_vector_type(4)));

#define GLDS(gp, lp)                                                                   \
  __builtin_amdgcn_global_load_lds((const __attribute__((address_space(1))) void*)(gp), \
                                   (__attribute__((address_space(3))) void*)(lp), 16, 0, 0)

// C[m][n] = sum_{k<1024} A[m*1024+k] * B[n*2048+koff+k], out bf16.
// trans=0: out[m*2048+n].  trans=1 (SWT): m=(blk*48+s) -> out[(blk*2048+n)*64+s].
__global__ __launch_bounds__(256) void gemm_flex_kernel(
    const u16* __restrict__ A, const u16* __restrict__ B, u16* __restrict__ Cout,
    int koff, int trans) {
  __shared__ u16 As[128 * 32];
  __shared__ u16 Bs[128 * 32];
  const int tid = threadIdx.x;
  const int lane = tid & 63;
  const int wave = tid >> 6;
  const int wm = (wave >> 1) * 64;
  const int wn = (wave & 1) * 64;
  const int bm = blockIdx.x * 128;
  const int bn = blockIdx.y * 128;
  const int lr = lane & 15;
  const int lq = lane >> 4;
  f32x4 acc[4][4] = {};
  const int e0 = tid * 8;
  const int r0 = e0 >> 5;
  const int c0 = e0 & 31;
  const u16* Ag0 = A + (size_t)(bm + r0) * 1024 + c0;
  const u16* Ag1 = A + (size_t)(bm + r0 + 64) * 1024 + c0;
  const u16* Bg0 = B + (size_t)(bn + r0) * 2048 + koff + c0;
  const u16* Bg1 = B + (size_t)(bn + r0 + 64) * 2048 + koff + c0;
  u16* As0 = As + e0; u16* As1 = As + e0 + 2048;
  u16* Bs0 = Bs + e0; u16* Bs1 = Bs + e0 + 2048;
  for (int k0 = 0; k0 < 1024; k0 += 32) {
    GLDS(Ag0 + k0, As0);
    GLDS(Ag1 + k0, As1);
    GLDS(Bg0 + k0, Bs0);
    GLDS(Bg1 + k0, Bs1);
    __syncthreads();
    bf16x8 af[4], bfr[4];
#pragma unroll
    for (int mi = 0; mi < 4; mi++)
      af[mi] = *(const bf16x8*)&As[(wm + mi * 16 + lr) * 32 + lq * 8];
#pragma unroll
    for (int ni = 0; ni < 4; ni++)
      bfr[ni] = *(const bf16x8*)&Bs[(wn + ni * 16 + lr) * 32 + lq * 8];
#pragma unroll
    for (int mi = 0; mi < 4; mi++)
#pragma unroll
      for (int ni = 0; ni < 4; ni++)
        acc[mi][ni] = __builtin_amdgcn_mfma_f32_16x16x32_bf16(af[mi], bfr[ni], acc[mi][ni], 0, 0, 0);
    __syncthreads();
  }
#pragma unroll
  for (int mi = 0; mi < 4; mi++) {
#pragma unroll
    for (int ni = 0; ni < 4; ni++) {
      const int col = bn + wn + ni * 16 + lr;
      const int rowb = bm + wm + mi * 16 + lq * 4;
      if (!trans) {
#pragma unroll
        for (int r = 0; r < 4; r++)
          Cout[(size_t)(rowb + r) * 2048 + col] = f2bf(acc[mi][ni][r]);
      } else {
#pragma unroll
        for (int r = 0; r < 4; r++) {
          const int m = rowb + r;
          const int blk = m / 48, s = m - blk * 48;
          Cout[((size_t)blk * 2048 + col) * 64 + s] = f2bf(acc[mi][ni][r]);
        }
      }
    }
  }
}

// E[m][n] = sum_k imgbf[m][k]*capbf[n][k], fp32 out, M=N=1536, K=1024. grid (12,12)
__global__ __launch_bounds__(256) void gemm_e_kernel(
    const u16* __restrict__ A, const u16* __restrict__ B, float* __restrict__ C) {
  __shared__ u16 As[128 * 32];
  __shared__ u16 Bs[128 * 32];
  const int tid = threadIdx.x;
  const int lane = tid & 63;
  const int wave = tid >> 6;
  const int wm = (wave >> 1) * 64;
  const int wn = (wave & 1) * 64;
  const int bm = blockIdx.x * 128;
  const int bn = blockIdx.y * 128;
  const int lr = lane & 15;
  const int lq = lane >> 4;
  f32x4 acc[4][4] = {};
  const int e0 = tid * 8;
  const int r0 = e0 >> 5;
  const int c0 = e0 & 31;
  const u16* Ag0 = A + (size_t)(bm + r0) * 1024 + c0;
  const u16* Ag1 = A + (size_t)(bm + r0 + 64) * 1024 + c0;
  const u16* Bg0 = B + (size_t)(bn + r0) * 1024 + c0;
  const u16* Bg1 = B + (size_t)(bn + r0 + 64) * 1024 + c0;
  u16* As0 = As + e0; u16* As1 = As + e0 + 2048;
  u16* Bs0 = Bs + e0; u16* Bs1 = Bs + e0 + 2048;
  for (int k0 = 0; k0 < 1024; k0 += 32) {
    GLDS(Ag0 + k0, As0);
    GLDS(Ag1 + k0, As1);
    GLDS(Bg0 + k0, Bs0);
    GLDS(Bg1 + k0, Bs1);
    __syncthreads();
    bf16x8 af[4], bfr[4];
#pragma unroll
    for (int mi = 0; mi < 4; mi++)
      af[mi] = *(const bf16x8*)&As[(wm + mi * 16 + lr) * 32 + lq * 8];
#pragma unroll
    for (int ni = 0; ni < 4; ni++)
      bfr[ni] = *(const bf16x8*)&Bs[(wn + ni * 16 + lr) * 32 + lq * 8];
#pragma unroll
    for (int mi = 0; mi < 4; mi++)
#pragma unroll
      for (int ni = 0; ni < 4; ni++)
        acc[mi][ni] = __builtin_amdgcn_mfma_f32_16x16x32_bf16(af[mi], bfr[ni], acc[mi][ni], 0, 0, 0);
    __syncthreads();
  }
#pragma unroll
  for (int mi = 0; mi < 4; mi++)
#pragma unroll
    for (int ni = 0; ni < 4; ni++) {
      const int col = bn + wn + ni * 16 + lr;
      const int rowb = bm + wm + mi * 16 + lq * 4;
#pragma unroll
      for (int r = 0; r < 4; r++)
        C[(size_t)(rowb + r) * 1536 + col] = acc[mi][ni][r];
    }
}

// ---------------------------------------------------------------- wcgate GEMM
// u-rows: M = P*NQ, m = pl*NQ+q, pairs sIdx-grouped (sIdx = (p0+pl)>>5).
// acc[m][n] = attnTg[m][0:64].SWT[sIdx][n][0:64]  (+ STEP==1: q1[m][0:1024].Wcat[n][0:1024])
// Tile BM x 256, BK=64, 8 waves (2Mx4N, per-wave BM/2 x 64), 2-phase dbuf;
// XOR-swizzled LDS (linear dest + pre-swizzled global col + same XOR on ds_read).
// Plain raster (XCD steering measured harmful on this chip: R11 FETCH unchanged,
// dur +20%). STEP==0: BM=128, qv+QW0 staged in the single-tile latency window.
// STEP==1: BM=256 (t2i) / 192 (i2t); qvS/stash overlay the dead dbuf halves.
template <int STEP, int NQ, int BM>
__global__ __launch_bounds__(512) void wcgate_kernel(
    const u16* __restrict__ attnTg, const u16* __restrict__ q2nd,
    const u16* __restrict__ qref, const u16* __restrict__ SWT,
    const u16* __restrict__ Wcat, const u16* __restrict__ qw0,
    const float* __restrict__ bl, const float* __restrict__ bg,
    u16* __restrict__ Uout, int p0, int swz) {
  constexpr int NT = (STEP == 1) ? 17 : 1;     // K tiles of 64
  constexpr int BUF = (BM + 256) * 64;         // u16 per buffer (A tile + B tile)
  constexpr int WMR = BM / 32;                 // per-wave M fragments
  constexpr int APASS = BM / 64;               // A staging passes of 512 chunks
  constexpr int QPASS = BM / 32;               // qv staging / stash-store passes
  __shared__ u16 sh[(STEP == 0) ? 73728 : 2 * BUF];
  const int tid = threadIdx.x;
  const int lane = tid & 63;
  const int wave = tid >> 6;
  const int wr = wave >> 2, wc = wave & 3;
  const int wm = wr * (BM / 2), wn = wc * 64;
  const int lr = lane & 15, lq = lane >> 4;
  const int b = blockIdx.y * 8 + blockIdx.x;
  int bmi, bni;
  if (swz) { bmi = (b & 7) + (b >> 6) * 8; bni = (b >> 3) & 7; }
  else     { bmi = blockIdx.y; bni = blockIdx.x; }
  const int bm = bmi * BM;
  const int bn = bni * 256;
  const int sIdx = (p0 + bm / NQ) >> 5;
  f32x4 acc[WMR][4] = {};

  // per-thread staging descriptors, swizzled source col
  int aoff[APASS]; const u16* asrc0[APASS]; const u16* asrcW[APASS];
  int boff[4]; const u16* bsrc0[4]; const u16* bsrcW[4];
#pragma unroll
  for (int p = 0; p < APASS; p++) {
    const int c = p * 512 + tid;
    const int row = c >> 3, sub = c & 7;
    const int sw = (sub ^ (row & 7)) << 3;
    aoff[p] = c * 8;
    asrc0[p] = attnTg + (size_t)(bm + row) * 64 + sw;
    asrcW[p] = q2nd + (size_t)(bm + row) * 1024 + sw;
  }
#pragma unroll
  for (int p = 0; p < 4; p++) {
    const int c = p * 512 + tid;
    const int row = c >> 3, sub = c & 7;
    const int sw = (sub ^ (row & 7)) << 3;
    boff[p] = c * 8;
    bsrc0[p] = SWT + ((size_t)sIdx * 2048 + bn + row) * 64 + sw;
    bsrcW[p] = Wcat + (size_t)(bn + row) * 2048 + sw;
  }

  u16* const qvS = (STEP == 0) ? sh + 24576 : sh + BUF;    // [BM][128] u16
  u16* const qw0S = sh + 40960;                            // [128][256] u16 (step0)
  u16* const stash = sh;                                   // [BM][128] u16 overlay

  auto epi_stage = [&]() {
#pragma unroll
    for (int p = 0; p < QPASS; p++) {          // qv: BM x 128 u16
      const int c = p * 512 + tid;
      const int row = c >> 4, j = c & 15;
      const u16* src;
      if (STEP == 1) {
        src = qref + (size_t)(bm + row) * 1024 + (bn >> 1) + j * 8;
      } else {
        const int m = bm + row;
        const int pl = m / NQ;                 // compile-time NQ -> magic mul
        const int q = m - pl * NQ;
        const int gs = ((p0 + pl) & 31) * 48 + q;
        src = qref + (size_t)gs * 1024 + (bn >> 1) + j * 8;
      }
      GLDS(src, qvS + c * 8);
    }
    if (STEP == 0) {
#pragma unroll
      for (int p = 0; p < 8; p++) {            // qw0 pairs: 128 x 256 u16 (512B rows)
        const int c = p * 512 + tid;
        const int row = c >> 5, j = c & 31;
        const int m = bm + row;
        const int pl = m / NQ;
        const int q = m - pl * NQ;
        const int gs = ((p0 + pl) & 31) * 48 + q;
        GLDS(qw0 + (size_t)gs * 2048 + bn + j * 8, qw0S + c * 8);
      }
    }
  };

  auto compute = [&](const u16* A, const u16* B) {
#pragma unroll
    for (int kk = 0; kk < 2; kk++) {
      bf16x8 bfv[4];
#pragma unroll
      for (int ni = 0; ni < 4; ni++) {
        const int rb = wn + ni * 16 + lr;
        bfv[ni] = *(const bf16x8*)&B[rb * 64 + ((kk * 32 + lq * 8) ^ ((rb & 7) << 3))];
      }
#pragma unroll
      for (int mi = 0; mi < WMR; mi++) {
        const int ra = wm + mi * 16 + lr;
        const bf16x8 af = *(const bf16x8*)&A[ra * 64 + ((kk * 32 + lq * 8) ^ ((ra & 7) << 3))];
#pragma unroll
        for (int ni = 0; ni < 4; ni++)
          acc[mi][ni] = __builtin_amdgcn_mfma_f32_16x16x32_bf16(af, bfv[ni], acc[mi][ni], 0, 0, 0);
      }
    }
  };

  if constexpr (STEP == 0) {
    // single SWT K-tile; epilogue operands staged in the same latency window
#pragma unroll
    for (int p = 0; p < APASS; p++) GLDS(asrc0[p], sh + aoff[p]);
#pragma unroll
    for (int p = 0; p < 4; p++) GLDS(bsrc0[p], sh + BM * 64 + boff[p]);
    epi_stage();                               // 12 more GLDS per thread in flight
    asm volatile("s_waitcnt vmcnt(12)" ::: "memory");  // first 6 (tile 0) landed
    __builtin_amdgcn_sched_barrier(0);
    __builtin_amdgcn_s_barrier();
    compute(sh, sh + BM * 64);
    __syncthreads();                           // drains epi GLDS + LDS reads
  } else {
    // tile 0 = attnTg/SWT; tiles 1..16 = q2nd/Wcat with kt = tt
#pragma unroll
    for (int p = 0; p < APASS; p++) GLDS(asrc0[p], sh + aoff[p]);
#pragma unroll
    for (int p = 0; p < 4; p++) GLDS(bsrc0[p], sh + BM * 64 + boff[p]);
    __syncthreads();
#pragma unroll
    for (int tt = 0; tt < NT; ++tt) {
      u16* cur = sh + (tt & 1) * BUF;
      u16* nxt = sh + ((tt & 1) ^ 1) * BUF;
      if (tt < NT - 1) {                       // stage Wcat tile kt=tt into nxt
#pragma unroll
        for (int p = 0; p < APASS; p++) GLDS(asrcW[p] + tt * 64, nxt + aoff[p]);
#pragma unroll
        for (int p = 0; p < 4; p++) GLDS(bsrcW[p] + tt * 64, nxt + BM * 64 + boff[p]);
      } else {
        epi_stage();                           // qv loads fly under last compute
      }
      compute(cur, cur + BM * 64);
      __syncthreads();                         // drains vmcnt + lgkm
    }
  }

  // pairwise epilogue: even lane owns row base+rr, odd lane row base+rr+1
  const bool evn = (lane & 1) == 0;
#pragma unroll
  for (int ni = 0; ni < 4; ni++) {
    const int ncol = wn + ni * 16 + lr;        // local n in [0,256)
    const int dloc = ncol >> 1;                // local d in [0,128), same for pair
    const float blv = bl[(bn >> 1) + dloc];
    const float bgv = bg[(bn >> 1) + dloc];
#pragma unroll
    for (int mi = 0; mi < WMR; mi++) {
      const int base = wm + mi * 16 + lq * 4;
#pragma unroll
      for (int rr = 0; rr < 4; rr += 2) {
        const float a0 = acc[mi][ni][rr];
        const float a1 = acc[mi][ni][rr + 1];
        const float o0 = __shfl_xor(a0, 1, 64);
        const float o1 = __shfl_xor(a1, 1, 64);
        float lin2 = (evn ? a0 : o1) + blv;
        float gt = (evn ? o0 : a1) + bgv;
        const int rl = base + rr + (evn ? 0 : 1);
        if constexpr (STEP == 0) {
          const u32 pair = *(const u32*)&qw0S[rl * 256 + dloc * 2];
          lin2 += bf2f((u16)(pair & 0xffffu));
          gt += bf2f((u16)(pair >> 16));
        }
        const float qv = bf2f(qvS[rl * 128 + dloc]);
        lin2 = fminf(fmaxf(lin2, -30.f), 30.f);
        gt = fminf(fmaxf(gt, -30.f), 30.f);
        const float gg = 1.f / (1.f + __expf(-gt));
        const float e2 = __expf(-2.f * lin2);
        const float th = (1.f - e2) / (1.f + e2);
        const float u = qv * gg + th * (1.f - gg);
        stash[rl * 128 + dloc] = f2bf(u);
      }
    }
  }
  __syncthreads();
  // coalesced store of BM x 128 u16 tile
#pragma unroll
  for (int p = 0; p < QPASS; p++) {
    const int c = p * 512 + tid;
    const int row = c >> 4, j = c & 15;
    *(bf16x8*)(Uout + (size_t)(bm + row) * 1024 + (bn >> 1) + j * 8) =
        *(const bf16x8*)&stash[row * 128 + j * 8];
  }
}

// q_new = u / (||u|| + eps), in-place (M x 1024 bf16). One wave per row.
__global__ __launch_bounds__(256) void qnorm_kernel(u16* __restrict__ Q) {
  const int m = blockIdx.x * 4 + (threadIdx.x >> 6);
  const int lane = threadIdx.x & 63;
  u16* p = Q + (size_t)m * 1024;
  float v[16];
  float ss = 0.f;
#pragma unroll
  for (int t = 0; t < 4; t++) {
    ushort4 uv = *(const ushort4*)&p[t * 256 + lane * 4];
    float a = bf2f(uv.x), b = bf2f(uv.y), c = bf2f(uv.z), dd = bf2f(uv.w);
    v[t * 4 + 0] = a; v[t * 4 + 1] = b; v[t * 4 + 2] = c; v[t * 4 + 3] = dd;
    ss += a * a + b * b + c * c + dd * dd;
  }
  ss = wave_red_sum(ss);
  const float inv = 1.f / (sqrtf(ss) + EPSF);
#pragma unroll
  for (int t = 0; t < 4; t++) {
    ushort4 ov;
    ov.x = f2bf(v[t * 4 + 0] * inv); ov.y = f2bf(v[t * 4 + 1] * inv);
    ov.z = f2bf(v[t * 4 + 2] * inv); ov.w = f2bf(v[t * 4 + 3] * inv);
    *(ushort4*)&p[t * 256 + lane * 4] = ov;
  }
}

// ---------------------------------------------------------------- fused attention step
// A (steps 1,2): QK^T MFMA; step0: logits = E block. B: leaky/l2norm/softmax (fp32).
// C': num = a.E-col, pss = a^T SS a (LDS algebra). Writes attnT (steps 0,1).
template <int NS, int NQ>
__global__ __launch_bounds__(256) void attn_step_kernel(
    const u16* __restrict__ Sbf, const float* __restrict__ E,
    const float* __restrict__ SS, const float* __restrict__ refn,
    const u16* __restrict__ qsrc, u16* __restrict__ attnTg,
    const int* __restrict__ dup, float* __restrict__ total,
    int p0, int t2i, int step) {
  constexpr int NQW = NQ / 4;
  const int pl = blockIdx.x;
  const int plg = p0 + pl;                 // pairs sIdx-grouped
  const int sIdx = plg >> 5, rIdx = plg & 31;
  const int c = t2i ? rIdx : sIdx;
  const int i = t2i ? sIdx : rIdx;
  const int gp = c * 32 + i;
  const u16* Sb = Sbf + (size_t)sIdx * 48 * 1024;
  const float* rn = refn + (size_t)rIdx * NQ;
  const u16* Qb = qsrc + (size_t)pl * NQ * 1024;

  __shared__ float redbuf[9600];   // phase A red[4][2400]; later Elw[48*65] + SSl[48*65]
  __shared__ float attnS[2304];
  __shared__ float redcos[48];
  float* Elw = redbuf;
  float* SSl = redbuf + 3120;

  const int tid = threadIdx.x;
  const int lane = tid & 63, wave = tid >> 6;
  const int lr = lane & 15, quad = lane >> 4;

  if (step == 0) {
    for (int e = tid; e < 2304; e += 256) {
      int s, q; float v;
      if (t2i) { s = e / 48; q = e - s * 48; v = E[(size_t)(i * 48 + s) * 1536 + c * 48 + q]; }
      else     { q = e / 48; s = e - q * 48; v = E[(size_t)(i * 48 + q) * 1536 + c * 48 + s]; }
      attnS[s * 48 + q] = v;
    }
  } else {
    // phase A: wave w covers k in [w*256, w*256+256); 8 slabs x 3x3 MFMA frags
    f32x4 acc[3][3] = {};
    const int kw = wave * 256;
    const u16* Arow[3]; const u16* Brow[3];
#pragma unroll
    for (int a = 0; a < 3; a++) {
      Arow[a] = Sb + (size_t)(a * 16 + lr) * 1024 + quad * 8;
      Brow[a] = Qb + (size_t)(a * 16 + lr) * 1024 + quad * 8;
    }
    bf16x8 A0[3], B0[3], A1[3], B1[3];
#pragma unroll
    for (int a = 0; a < 3; a++) {
      A0[a] = *(const bf16x8*)(Arow[a] + kw);
      B0[a] = *(const bf16x8*)(Brow[a] + kw);
    }
#pragma unroll
    for (int j = 0; j < 8; j++) {
      if (j < 7) {
        const int kn = kw + (j + 1) * 32;
#pragma unroll
        for (int a = 0; a < 3; a++) {
          A1[a] = *(const bf16x8*)(Arow[a] + kn);
          B1[a] = *(const bf16x8*)(Brow[a] + kn);
        }
      }
#pragma unroll
      for (int a = 0; a < 3; a++)
#pragma unroll
        for (int b = 0; b < 3; b++)
          acc[a][b] = __builtin_amdgcn_mfma_f32_16x16x32_bf16(A0[a], B0[b], acc[a][b], 0, 0, 0);
#pragma unroll
      for (int a = 0; a < 3; a++) { A0[a] = A1[a]; B0[a] = B1[a]; }
    }
    float* myred = redbuf + wave * 2400;
#pragma unroll
    for (int a = 0; a < 3; a++)
#pragma unroll
      for (int b = 0; b < 3; b++) {
        const int col = b * 16 + lr;
        const int row0 = a * 16 + quad * 4;
#pragma unroll
        for (int r = 0; r < 4; r++)
          myred[(row0 + r) * 50 + col] = acc[a][b][r];
      }
    __syncthreads();
#pragma unroll
    for (int t = 0; t < 9; t++) {
      const int e = tid + t * 256;
      const int s = e / 48, q = e - s * 48;
      const int o = s * 50 + q;
      attnS[e] = redbuf[o] + redbuf[2400 + o] + redbuf[4800 + o] + redbuf[7200 + o];
    }
  }
  __syncthreads();
  // load Elw / SSl (into dead red space) + leaky/l2norm in one interval
  for (int e = tid; e < 2304; e += 256) {
    int s, q; float v;
    if (t2i) { s = e / 48; q = e - s * 48; v = E[(size_t)(i * 48 + s) * 1536 + c * 48 + q]; }
    else     { q = e / 48; s = e - q * 48; v = E[(size_t)(i * 48 + q) * 1536 + c * 48 + s]; }
    Elw[s * 65 + q] = v;
  }
  for (int e = tid; e < 48 * 64; e += 256) {
    const int s = e >> 6, s2 = e & 63;
    SSl[s * 65 + s2] = SS[((size_t)sIdx * 48 + s) * 64 + s2];
  }
  if (tid < NS) {
    float row[NQ];
    float ss = 0.f;
#pragma unroll
    for (int q = 0; q < NQ; q++) {
      float v = attnS[tid * 48 + q];
      v = (v > 0.f) ? v : SLOPEF * v;
      row[q] = v; ss += v * v;
    }
    const float inv = 1.f / (sqrtf(ss) + EPSF);
#pragma unroll
    for (int q = 0; q < NQ; q++) attnS[tid * 48 + q] = row[q] * inv;
  }
  __syncthreads();
  if (tid < NQ) {
    float mx = -1e30f;
#pragma unroll
    for (int s = 0; s < NS; s++) mx = fmaxf(mx, attnS[s * 48 + tid]);
    float ex[NS]; float sum = 0.f;
#pragma unroll
    for (int s = 0; s < NS; s++) {
      float t = __expf(SMOOTHF * (attnS[s * 48 + tid] - mx));
      ex[s] = t; sum += t;
    }
    const float inv = 1.f / sum;
#pragma unroll
    for (int s = 0; s < NS; s++) attnS[s * 48 + tid] = ex[s] * inv;
  }
  __syncthreads();
  // write attnT rows (steps 0,1): [m = pl*NQ+q][64 s]
  if (step < 2) {
    for (int e = tid; e < NQ * 64; e += 256) {
      const int q = e >> 6, s = e & 63;
      attnTg[((size_t)(pl * NQ + q)) * 64 + s] = (s < 48) ? f2bf(attnS[s * 48 + q]) : (u16)0;
    }
  }
  // phase C': per-q num & pss via E/SS algebra
  {
    const int qbase = wave * NQW;
#pragma unroll
    for (int qq = 0; qq < NQW; qq++) {
      const int q = qbase + qq;
      const float a_l = (lane < 48) ? attnS[lane * 48 + q] : 0.f;
      float t = 0.f;
#pragma unroll
      for (int s = 0; s < NS; s++)
        t += attnS[s * 48 + q] * SSl[s * 65 + lane];
      float pssv = wave_red_sum(a_l * t);
      float numv = wave_red_sum(a_l * Elw[lane * 65 + q]);
      if (lane == 0) redcos[q] = numv / fmaxf(rn[q] * sqrtf(pssv), EPSF);
    }
  }
  __syncthreads();
  if (tid == 0) {
    float sim = 0.f;
#pragma unroll
    for (int q = 0; q < NQ; q++) sim += redcos[q];
    sim *= (1.0f / NQ);
    atomicAdd(&total[gp], dup[gp] ? -1.0f : sim);
  }
}

// ---------------------------------------------------------------- launcher
extern "C" void kernel_launch(void* const* d_in, const int* in_sizes, int n_in,
                              void* d_out, int out_size, void* d_ws, size_t ws_size,
                              hipStream_t stream) {
  (void)in_sizes; (void)n_in;
  const float* img = (const float*)d_in[0];
  const float* cap = (const float*)d_in[1];
  const float* W_lt2i = (const float*)d_in[2];
  const float* b_lt2i = (const float*)d_in[3];
  const float* W_gt2i = (const float*)d_in[4];
  const float* b_gt2i = (const float*)d_in[5];
  const float* W_li2t = (const float*)d_in[6];
  const float* b_li2t = (const float*)d_in[7];
  const float* W_gi2t = (const float*)d_in[8];
  const float* b_gi2t = (const float*)d_in[9];
  float* total = (float*)d_out;

  char* ws = (char*)d_ws;
  size_t off = 0;
  auto alloc = [&](size_t b) { void* p = ws + off; off += (b + 255) & ~(size_t)255; return p; };
  u16* Wcat = (u16*)alloc((size_t)2048 * 2048 * 2);
  u16* imgbf = (u16*)alloc((size_t)32 * 48 * 1024 * 2);
  u16* capbf = (u16*)alloc((size_t)32 * 48 * 1024 * 2);
  float* capn = (float*)alloc(1280 * 4);
  float* imgn = (float*)alloc(1152 * 4);
  int* dupb = (int*)alloc(1024 * 4);
  u16* SWT = (u16*)alloc((size_t)32 * 2048 * 64 * 2);
  float* E = (float*)alloc((size_t)1536 * 1536 * 4);
  float* SSi = (float*)alloc((size_t)32 * 48 * 64 * 4);
  float* SSc = (float*)alloc((size_t)32 * 48 * 64 * 4);
  u16* QW0 = (u16*)alloc((size_t)1536 * 2048 * 2);
  const size_t fixed = off;

  static const int cands[6] = {1024, 512, 256, 128, 64, 32};
  int P = 32;
  for (int ci = 0; ci < 6; ci++) {
    const int cand = cands[ci];
    const size_t cA = (((size_t)cand * 40 * 1024 * 2) + 255) & ~(size_t)255;
    const size_t aT = (((size_t)cand * 40 * 64 * 2) + 255) & ~(size_t)255;
    if (fixed + 2 * cA + aT <= ws_size) { P = cand; break; }
  }
  u16* catA = (u16*)alloc((size_t)P * 40 * 1024 * 2);
  u16* catB = (u16*)alloc((size_t)P * 40 * 1024 * 2);
  u16* attnTg = (u16*)alloc((size_t)P * 40 * 64 * 2);

  hipMemsetAsync(d_out, 0, (size_t)out_size * sizeof(float), stream);
  hipMemsetAsync(SWT, 0, (size_t)32 * 2048 * 64 * 2, stream);
  rownorm_kernel<<<dim3(2432), dim3(256), 0, stream>>>(cap, img, capn, imgn);
  dup_kernel<<<dim3(1024), dim3(256), 0, stream>>>(cap, dupb);
  bfpad_kernel<<<dim3(1536), dim3(256), 0, stream>>>(cap, capbf, 40);
  bfpad_kernel<<<dim3(1536), dim3(256), 0, stream>>>(img, imgbf, 36);
  gemm_e_kernel<<<dim3(12, 12), dim3(256), 0, stream>>>(imgbf, capbf, E);
  ss_kernel<<<dim3(48, 32), dim3(256), 0, stream>>>(img, SSi, 36);
  ss_kernel<<<dim3(48, 32), dim3(256), 0, stream>>>(cap, SSc, 40);

  const int nch = 1024 / P;
  for (int dir = 0; dir < 2; dir++) {
    const int t2i = (dir == 0) ? 1 : 0;
    const float* Wl = t2i ? W_lt2i : W_li2t;
    const float* Wg = t2i ? W_gt2i : W_gi2t;
    const float* bl = t2i ? b_lt2i : b_li2t;
    const float* bg = t2i ? b_gt2i : b_gi2t;
    const u16* Sbf = t2i ? imgbf : capbf;
    const u16* Refbf = t2i ? capbf : imgbf;
    const float* SSd = t2i ? SSi : SSc;
    const float* refn = t2i ? capn : imgn;
    const int NQ = t2i ? 40 : 36;
    const int BM1 = t2i ? 256 : 192;           // step-1 tile (sIdx-group aligned)
    const int Mrows = P * NQ;
    const int Mt0 = Mrows / 128;
    const int Mt1 = Mrows / BM1;
    const int swz0 = (Mt0 % 8 == 0) ? 1 : 0;
    const int swz1 = (Mt1 % 8 == 0) ? 1 : 0;
    wconv_kernel<<<dim3(4096), dim3(256), 0, stream>>>(Wl, Wg, Wcat);
    gemm_flex_kernel<<<dim3(12, 16), dim3(256), 0, stream>>>(Sbf, Wcat, SWT, 1024, 1);
    gemm_flex_kernel<<<dim3(12, 16), dim3(256), 0, stream>>>(Refbf, Wcat, QW0, 0, 0);
    for (int ch = 0; ch < nch; ch++) {
      const int p0 = ch * P;
      for (int step = 0; step < 3; step++) {
        const u16* qsrc = (step == 1) ? catB : catA;
        if (t2i)
          attn_step_kernel<36, 40><<<dim3(P), dim3(256), 0, stream>>>(
              Sbf, E, SSd, refn, qsrc, attnTg, dupb, total, p0, 1, step);
        else
          attn_step_kernel<40, 36><<<dim3(P), dim3(256), 0, stream>>>(
              Sbf, E, SSd, refn, qsrc, attnTg, dupb, total, p0, 0, step);
        if (step == 0) {
          if (t2i)
            wcgate_kernel<0, 40, 128><<<dim3(8, Mt0), dim3(512), 0, stream>>>(
                attnTg, catA, Refbf, SWT, Wcat, QW0, bl, bg, catB, p0, swz0);
          else
            wcgate_kernel<0, 36, 128><<<dim3(8, Mt0), dim3(512), 0, stream>>>(
                attnTg, catA, Refbf, SWT, Wcat, QW0, bl, bg, catB, p0, swz0);
          qnorm_kernel<<<dim3(Mrows / 4), dim3(256), 0, stream>>>(catB);
        } else if (step == 1) {
          if (t2i)
            wcgate_kernel<1, 40, 256><<<dim3(8, Mt1), dim3(512), 0, stream>>>(
                attnTg, catB, catB, SWT, Wcat, QW0, bl, bg, catA, p0, swz1);
          else
            wcgate_kernel<1, 36, 192><<<dim3(8, Mt1), dim3(512), 0, stream>>>(
                attnTg, catB, catB, SWT, Wcat, QW0, bl, bg, catA, p0, swz1);
          qnorm_kernel<<<dim3(Mrows / 4), dim3(256), 0, stream>>>(catA);
        }
      }
    }
  }
}